// Round 4
// baseline (325.049 us; speedup 1.0000x reference)
//
#include <hip/hip_runtime.h>

#define N 128
#define NN 16384            // N*N
#define M 2048
#define CHUNKS 131072       // per array: M * (NN/4) / 64  (1 KiB chunks)
#define WAVES 8192          // 2048 blocks * 4 waves
#define STEPS 32            // 2*CHUNKS / WAVES

// ws layout (floats):
// [0..512)    E: float4 per column j: (e0r_j, e0i_j, e1r_j, e1i_j)
// [512..1024) G: float4 per row  i: (l0*e0r_i, l0*e0i_i, l1*e1r_i, l1*e1i_i)
// [1024..3072) accR[2048] | [3072..5120) accI[2048]   (zeroed each call)

__device__ __forceinline__ float block_reduce128(float v, float* red, int i) {
    __syncthreads();
    red[i] = v;
    __syncthreads();
    for (int off = 64; off > 0; off >>= 1) {
        if (i < off) red[i] += red[i + off];
        __syncthreads();
    }
    return red[0];
}

__global__ void prep_kernel(const float* __restrict__ theta,
                            const float* __restrict__ evl,
                            float* __restrict__ ws) {
    __shared__ float red[N];
    const int i = threadIdx.x;   // 128 threads

    float c0r = theta[i], c0i = theta[N + i];
    float s0 = block_reduce128(c0r * c0r + c0i * c0i, red, i);
    float inv0 = rsqrtf(s0);
    float a0r = c0r * inv0, a0i = c0i * inv0;

    // c1 -= vdot(evc0, c1) * evc0   (vdot conjugates first arg)
    float c1r = theta[2 * N + i], c1i = theta[3 * N + i];
    float dr = block_reduce128(a0r * c1r + a0i * c1i, red, i);
    float di = block_reduce128(a0r * c1i - a0i * c1r, red, i);
    c1r -= dr * a0r - di * a0i;
    c1i -= dr * a0i + di * a0r;

    float s1 = block_reduce128(c1r * c1r + c1i * c1i, red, i);
    float inv1 = rsqrtf(s1);
    float a1r = c1r * inv1, a1i = c1i * inv1;

    float l0 = log1pf(expf(evl[0]));
    float l1 = log1pf(expf(evl[1]));
    float inl = rsqrtf(l0 * l0 + l1 * l1);
    l0 *= inl; l1 *= inl;

    float4* E4 = (float4*)ws;
    E4[i]       = make_float4(a0r, a0i, a1r, a1i);
    E4[128 + i] = make_float4(l0 * a0r, l0 * a0i, l1 * a1r, l1 * a1i);
}

// ---------------------------------------------------------------------------
// Lockstep grid-stride: global chunk id space [0, 2*CHUNKS); id < CHUNKS is
// basis_re, else basis_im. Chunk = 1 KiB = 2 rows of one k-matrix. Consecutive
// waves read adjacent chunks -> dense sweeping address front (m13 pattern).
// Per chunk: P = sum x*Hr, Q = sum x*Hi via rank-2 factorization; wave-reduce;
// lane0 atomically accumulates into per-k (vr, vi).
// ---------------------------------------------------------------------------
__global__ __launch_bounds__(256, 8) void dot_kernel(
        const float4* __restrict__ br, const float4* __restrict__ bi,
        const float* __restrict__ ws, float* __restrict__ accR,
        float* __restrict__ accI) {
    __shared__ __align__(16) float4 sG[N];
    const int t = threadIdx.x;
    if (t < N) sG[t] = ((const float4*)ws)[N + t];

    const int lane = t & 63;
    const int wave = t >> 6;
    const int wgid = blockIdx.x * 4 + wave;      // 0..8191

    // fixed column block for this lane -> E in registers
    const int j4 = lane & 31;
    const float4* E4 = (const float4*)ws;
    float4 E0 = E4[4 * j4 + 0];
    float4 E1 = E4[4 * j4 + 1];
    float4 E2 = E4[4 * j4 + 2];
    float4 E3 = E4[4 * j4 + 3];
    const int h = lane >> 5;
    __syncthreads();

    // depth-4 rotating prefetch across the grid-stride steps
    float4 buf[4];
    #pragma unroll
    for (int p = 0; p < 4; ++p) {
        const int cid = wgid + p * WAVES;        // all < CHUNKS (re array)
        buf[p] = br[(size_t)cid * 64 + lane];
    }

    #pragma unroll 4
    for (int s = 0; s < STEPS; ++s) {
        float4 a = buf[s & 3];
        if (s < STEPS - 4) {
            const int pid = wgid + (s + 4) * WAVES;
            const int aid = pid & (CHUNKS - 1);
            const float4* base = (pid < CHUNKS) ? br : bi;
            buf[s & 3] = base[(size_t)aid * 64 + lane];
        }

        const int cid  = wgid + s * WAVES;
        const int isRe = (cid < CHUNKS);
        const int aid  = cid & (CHUNKS - 1);
        const int k    = aid >> 6;
        const int lc   = aid & 63;

        float4 g = sG[2 * lc + h];
        float d0r = a.x * E0.x + a.y * E1.x + a.z * E2.x + a.w * E3.x;
        float d0i = a.x * E0.y + a.y * E1.y + a.z * E2.y + a.w * E3.y;
        float d1r = a.x * E0.z + a.y * E1.z + a.z * E2.z + a.w * E3.z;
        float d1i = a.x * E0.w + a.y * E1.w + a.z * E2.w + a.w * E3.w;
        float P = g.x * d0r + g.y * d0i - g.z * d1r - g.w * d1i;
        float Q = g.y * d0r - g.x * d0i - g.w * d1r + g.z * d1i;

        for (int off = 32; off > 0; off >>= 1) {
            P += __shfl_down(P, off);
            Q += __shfl_down(Q, off);
        }
        if (lane == 0) {
            // re-chunk: vr += P (x*Hr), vi += Q (x*Hi)
            // im-chunk: vr += Q (y*Hi), vi += -P (-y*Hr)
            atomicAdd(&accR[k], isRe ? P : Q);
            atomicAdd(&accI[k], isRe ? Q : -P);
        }
    }
}

__global__ __launch_bounds__(256) void reduce_kernel(
        const float* __restrict__ accR, const float* __restrict__ accI,
        float* __restrict__ out) {
    const int k = blockIdx.x * 256 + threadIdx.x;   // 2048 threads
    float vr = accR[k], vi = accI[k];
    float s = vr * vr + vi * vi;

    for (int off = 32; off > 0; off >>= 1) s += __shfl_down(s, off);
    __shared__ float sw[4];
    const int wave = threadIdx.x >> 6, lane = threadIdx.x & 63;
    if (lane == 0) sw[wave] = s;
    __syncthreads();
    if (threadIdx.x == 0)
        atomicAdd(out, sw[0] + sw[1] + sw[2] + sw[3]);
}

extern "C" void kernel_launch(void* const* d_in, const int* in_sizes, int n_in,
                              void* d_out, int out_size, void* d_ws, size_t ws_size,
                              hipStream_t stream) {
    const float* basis_re = (const float*)d_in[0];
    const float* basis_im = (const float*)d_in[1];
    const float* theta    = (const float*)d_in[2];
    const float* evl      = (const float*)d_in[3];
    float* out = (float*)d_out;
    float* ws  = (float*)d_ws;

    hipMemsetAsync(d_out, 0, sizeof(float), stream);
    hipMemsetAsync(ws + 1024, 0, 2 * M * sizeof(float), stream);  // accR|accI
    prep_kernel<<<1, 128, 0, stream>>>(theta, evl, ws);
    dot_kernel<<<WAVES / 4, 256, 0, stream>>>((const float4*)basis_re,
                                              (const float4*)basis_im,
                                              ws, ws + 1024, ws + 1024 + M);
    reduce_kernel<<<M / 256, 256, 0, stream>>>(ws + 1024, ws + 1024 + M, out);
}

// Round 5
// 290.557 us; speedup vs baseline: 1.1187x; 1.1187x over previous
//
#include <hip/hip_runtime.h>

#define N 128
#define NN 16384          // N*N
#define M 2048

// ws layout (floats):
// [0..512)     E: float4 per column j: (e0r_j, e0i_j, e1r_j, e1i_j)
// [512..1024)  G: float4 per row  i: (l0*e0r_i, l0*e0i_i, l1*e1r_i, l1*e1i_i)
// [1024..9216) job outputs: float2 per job (P, Q), 4096 jobs

__device__ __forceinline__ float block_reduce128(float v, float* red, int i) {
    __syncthreads();
    red[i] = v;
    __syncthreads();
    for (int off = 64; off > 0; off >>= 1) {
        if (i < off) red[i] += red[i + off];
        __syncthreads();
    }
    return red[0];
}

__global__ void prep_kernel(const float* __restrict__ theta,
                            const float* __restrict__ evl,
                            float* __restrict__ ws) {
    __shared__ float red[N];
    const int i = threadIdx.x;   // 128 threads

    float c0r = theta[i], c0i = theta[N + i];
    float s0 = block_reduce128(c0r * c0r + c0i * c0i, red, i);
    float inv0 = rsqrtf(s0);
    float a0r = c0r * inv0, a0i = c0i * inv0;

    // c1 -= vdot(evc0, c1) * evc0   (vdot conjugates first arg)
    float c1r = theta[2 * N + i], c1i = theta[3 * N + i];
    float dr = block_reduce128(a0r * c1r + a0i * c1i, red, i);
    float di = block_reduce128(a0r * c1i - a0i * c1r, red, i);
    c1r -= dr * a0r - di * a0i;
    c1i -= dr * a0i + di * a0r;

    float s1 = block_reduce128(c1r * c1r + c1i * c1i, red, i);
    float inv1 = rsqrtf(s1);
    float a1r = c1r * inv1, a1i = c1i * inv1;

    float l0 = log1pf(expf(evl[0]));
    float l1 = log1pf(expf(evl[1]));
    float inl = rsqrtf(l0 * l0 + l1 * l1);
    l0 *= inl; l1 *= inl;

    float4* E4 = (float4*)ws;
    E4[i]       = make_float4(a0r, a0i, a1r, a1i);
    E4[128 + i] = make_float4(l0 * a0r, l0 * a0i, l1 * a1r, l1 * a1i);
}

// ---------------------------------------------------------------------------
// One WAVE per job (k, re/im half). Wave streams one contiguous 64 KiB region
// computing P = sum x*Hr, Q = sum x*Hi via the rank-2 factorization:
//   Hr(i,j) = g0r_i*e0r_j + g0i_i*e0i_j - g1r_i*e1r_j - g1i_i*e1i_j
//   Hi(i,j) = g0i_i*e0r_j - g0r_i*e0i_j - g1i_i*e1r_j + g1r_i*e1i_j
// Per-lane column block fixed -> E in 16 registers. Depth-8 rotating prefetch
// (buf[8] = 32 VGPRs live) so 8 KiB/wave stays in flight.
// ---------------------------------------------------------------------------
__global__ __launch_bounds__(256, 4) void dot_kernel(
        const float4* __restrict__ br, const float4* __restrict__ bi,
        const float* __restrict__ ws, float2* __restrict__ jout) {
    __shared__ __align__(16) float4 sG[N];   // lambda-scaled row constants
    const int t = threadIdx.x;
    if (t < N) sG[t] = ((const float4*)ws)[N + t];

    const int lane = t & 63;
    const int wave = t >> 6;
    const int job  = blockIdx.x * 4 + wave;      // 4096 jobs
    const int k    = job >> 1;
    const float4* __restrict__ src =
        ((job & 1) ? bi : br) + (size_t)k * (NN / 4);

    // columns 4*j4 .. 4*j4+3 for this lane, invariant across the loop
    const int j4 = lane & 31;
    const float4* E4 = (const float4*)ws;
    float4 E0 = E4[4 * j4 + 0];
    float4 E1 = E4[4 * j4 + 1];
    float4 E2 = E4[4 * j4 + 2];
    float4 E3 = E4[4 * j4 + 3];
    const int h = lane >> 5;
    __syncthreads();                             // sG ready

    // depth-8 rotating prefetch (8 KiB per wave in flight)
    float4 buf[8];
    #pragma unroll
    for (int p = 0; p < 8; ++p) buf[p] = src[64 * p + lane];

    float P = 0.f, Q = 0.f;

#define BODY(a, c)                                                        \
    {                                                                     \
        float4 g = sG[2 * (c) + h];                                       \
        float d0r = a.x * E0.x + a.y * E1.x + a.z * E2.x + a.w * E3.x;    \
        float d0i = a.x * E0.y + a.y * E1.y + a.z * E2.y + a.w * E3.y;    \
        float d1r = a.x * E0.z + a.y * E1.z + a.z * E2.z + a.w * E3.z;    \
        float d1i = a.x * E0.w + a.y * E1.w + a.z * E2.w + a.w * E3.w;    \
        P += g.x * d0r + g.y * d0i - g.z * d1r - g.w * d1i;               \
        Q += g.y * d0r - g.x * d0i - g.w * d1r + g.z * d1i;               \
    }

    int c = 0;
    #pragma unroll 8
    for (; c < 56; ++c) {                        // steady state: 8 in flight
        float4 a = buf[c & 7];
        buf[c & 7] = src[64 * (c + 8) + lane];
        BODY(a, c)
    }
    #pragma unroll
    for (; c < 64; ++c) {                        // drain
        float4 a = buf[c & 7];
        BODY(a, c)
    }
#undef BODY

    // wave-64 reduction; lane 0 writes this job's (P, Q)
    for (int off = 32; off > 0; off >>= 1) {
        P += __shfl_down(P, off);
        Q += __shfl_down(Q, off);
    }
    if (lane == 0) jout[job] = make_float2(P, Q);
}

// ---------------------------------------------------------------------------
// Combine the two stream-partials per k, sum |v_k|^2.
// jout as float4[k] = (Pa, Qa, Pb, Qb); vr = Pa + Qb, vi = Qa - Pb.
// ---------------------------------------------------------------------------
__global__ __launch_bounds__(256) void reduce_kernel(
        const float4* __restrict__ jout4, float* __restrict__ out) {
    const int k = blockIdx.x * 256 + threadIdx.x;   // 2048 threads
    float4 f = jout4[k];
    float vr = f.x + f.w;
    float vi = f.y - f.z;
    float s = vr * vr + vi * vi;

    for (int off = 32; off > 0; off >>= 1) s += __shfl_down(s, off);
    __shared__ float sw[4];
    const int wave = threadIdx.x >> 6, lane = threadIdx.x & 63;
    if (lane == 0) sw[wave] = s;
    __syncthreads();
    if (threadIdx.x == 0)
        atomicAdd(out, sw[0] + sw[1] + sw[2] + sw[3]);
}

extern "C" void kernel_launch(void* const* d_in, const int* in_sizes, int n_in,
                              void* d_out, int out_size, void* d_ws, size_t ws_size,
                              hipStream_t stream) {
    const float* basis_re = (const float*)d_in[0];
    const float* basis_im = (const float*)d_in[1];
    const float* theta    = (const float*)d_in[2];
    const float* evl      = (const float*)d_in[3];
    float* out = (float*)d_out;
    float* ws  = (float*)d_ws;

    hipMemsetAsync(d_out, 0, sizeof(float), stream);
    prep_kernel<<<1, 128, 0, stream>>>(theta, evl, ws);
    dot_kernel<<<M / 2, 256, 0, stream>>>((const float4*)basis_re,
                                          (const float4*)basis_im,
                                          ws, (float2*)(ws + 1024));
    reduce_kernel<<<8, 256, 0, stream>>>((const float4*)(ws + 1024), out);
}